// Round 10
// baseline (571.284 us; speedup 1.0000x reference)
//
#include <hip/hip_runtime.h>
#include <hip/hip_fp16.h>
#include <math.h>

// LiquidNet2: B=1024, I=128, S=512, UNFOLDS=6, out v[B,S] fp32.
//
// Block = postsynaptic neuron j (512 blocks), thread = batch PAIR (512 thr).
// Whole sigmoid computed in PACKED f16 (v_pk_*_f16 = 2 elems/lane, full rate),
// zero transcendentals, zero LDS:
//   t = pk_fma(AC, v, AC)            op_sel broadcast: A*v + C (both halves)
//   t = clamp[-14, 13.5]             (pk_max/pk_min; bounds all bit-tricks)
//   z = t + 1536 (RNE -> k in mantissa); kf = z - 1536; f = t - kf (exact)
//   p = Taylor3(f)  (3 pk_fma)       2^f for f in [-0.5,0.5]
//   sc = 2^k via bits: (zbits - 26097) << 10   (pk_sub_u16 + pk_lshlrev_b16)
//   e = p*sc; d = e + 1
//   y = bits(0x7798 - dbits); q = d*y - 2; sn = y*q = -(1/d)   (1 packed NR;
//       systematic NR error cancels in num/den ratio)
//   acc via 4x v_fma_mix_f32: n_b += (-Wn)*sn_b ; d_b += (-Wp)*sn_b
// Params 8B/(i,j): u32 AC = f16(A,C), u32 WW = f16(-Wn,-Wp); [j][i] order ->
// wave-uniform s_load. A=-sigma*log2e, C=sigma*mu*log2e, Wn=W*erev, Wp=W.
// v stored f16, transposed vT[S][B]; 6 stream-ordered unfold launches.

#define B_TOT 1024
#define I_DIM 128
#define S_DIM 512
#define UNFOLDS 6
#define L2E 1.4426950408889634f

// ---- ws byte offsets ----
#define BY_RECH 0u                         // 512*512*8 = 2 MiB
#define BY_SENH (BY_RECH + 2097152u)       // 512*128*8 = 0.5 MiB
#define BY_XH   (BY_SENH + 524288u)        // 128*1024*2 = 0.25 MiB
#define BY_VA   (BY_XH + 262144u)          // 1 MiB (f16 [S][B])
#define BY_VB   (BY_VA + 1048576u)         // 1 MiB
#define BY_SN   (BY_VB + 1048576u)         // 2 MiB (f32 [S][B])
#define BY_SD   (BY_SN + 2097152u)         // 2 MiB
// total 8.75 MiB

struct Cst { unsigned kLO, kHI, k1536, c3, c2, c1, one2, m2, magic, c26097, sh10; };

__device__ __forceinline__ unsigned hpak(float x) {
    __half h = __float2half_rn(x);
    unsigned short b = __builtin_bit_cast(unsigned short, h);
    return ((unsigned)b << 16) | (unsigned)b;
}

__device__ __forceinline__ Cst mkc() {
    Cst c;
    c.kLO    = hpak(-14.0f);
    c.kHI    = hpak(13.5f);
    c.k1536  = hpak(1536.0f);
    c.c3     = hpak(0.05550411f);
    c.c2     = hpak(0.24022651f);
    c.c1     = hpak(0.69314718f);
    c.one2   = hpak(1.0f);
    c.m2     = hpak(-2.0f);
    c.magic  = 0x77987798u;
    c.c26097 = (26097u << 16) | 26097u;
    c.sh10   = (10u << 16) | 10u;
    return c;
}

// one i, batch pair: full packed-f16 sigmoid + mixed-precision accumulate
__device__ __forceinline__ void sigpair(unsigned AC, unsigned WW, unsigned vp,
                                        const Cst& C,
                                        float& n0, float& n1, float& d0, float& d1)
{
    unsigned t, z, kf, f, p, scb, sc, e, d, y, q, sn;
    asm("v_pk_fma_f16 %0, %1, %2, %1 op_sel:[0,0,1] op_sel_hi:[0,1,1]"
        : "=v"(t) : "s"(AC), "v"(vp));                       // t = A*v + C
    asm("v_pk_max_f16 %0, %0, %1" : "+v"(t) : "v"(C.kLO));
    asm("v_pk_min_f16 %0, %0, %1" : "+v"(t) : "v"(C.kHI));
    asm("v_pk_add_f16 %0, %1, %2" : "=v"(z) : "v"(t), "v"(C.k1536));
    asm("v_pk_add_f16 %0, %1, %2 neg_lo:[0,1] neg_hi:[0,1]"
        : "=v"(kf) : "v"(z), "v"(C.k1536));                  // kf = z - 1536 = round(t)
    asm("v_pk_add_f16 %0, %1, %2 neg_lo:[0,1] neg_hi:[0,1]"
        : "=v"(f) : "v"(t), "v"(kf));                        // f = t - kf (exact)
    asm("v_pk_fma_f16 %0, %1, %2, %3" : "=v"(p) : "v"(C.c3), "v"(f), "v"(C.c2));
    asm("v_pk_fma_f16 %0, %0, %1, %2" : "+v"(p) : "v"(f), "v"(C.c1));
    asm("v_pk_fma_f16 %0, %0, %1, %2" : "+v"(p) : "v"(f), "v"(C.one2));  // ~2^f
    asm("v_pk_sub_u16 %0, %1, %2" : "=v"(scb) : "v"(z), "v"(C.c26097));  // k+15
    asm("v_pk_lshlrev_b16 %0, %1, %2" : "=v"(sc) : "v"(C.sh10), "v"(scb)); // 2^k bits
    asm("v_pk_mul_f16 %0, %1, %2" : "=v"(e) : "v"(p), "v"(sc));          // 2^t
    asm("v_pk_add_f16 %0, %1, %2" : "=v"(d) : "v"(e), "v"(C.one2));      // 1+2^t
    asm("v_pk_sub_u16 %0, %1, %2" : "=v"(y) : "v"(C.magic), "v"(d));     // ~1/d
    asm("v_pk_fma_f16 %0, %1, %2, %3" : "=v"(q) : "v"(d), "v"(y), "v"(C.m2)); // dy-2
    asm("v_pk_mul_f16 %0, %1, %2" : "=v"(sn) : "v"(y), "v"(q));          // -(1/d)
    // n_b += (-Wn)*(-s_b); d_b += (-Wp)*(-s_b)
    asm("v_fma_mix_f32 %0, %1, %2, %0 op_sel:[0,0,0] op_sel_hi:[1,1,0]"
        : "+v"(n0) : "s"(WW), "v"(sn));
    asm("v_fma_mix_f32 %0, %1, %2, %0 op_sel:[0,1,0] op_sel_hi:[1,1,0]"
        : "+v"(n1) : "s"(WW), "v"(sn));
    asm("v_fma_mix_f32 %0, %1, %2, %0 op_sel:[1,0,0] op_sel_hi:[1,1,0]"
        : "+v"(d0) : "s"(WW), "v"(sn));
    asm("v_fma_mix_f32 %0, %1, %2, %0 op_sel:[1,1,0] op_sel_hi:[1,1,0]"
        : "+v"(d1) : "s"(WW), "v"(sn));
}

__device__ __forceinline__ void reduce_f16(
    const uint2* __restrict__ qp,       // [nd] param records for this j
    const unsigned* __restrict__ vrow,  // f16-pair rows [nd][B/2]
    int nd, int tid, const Cst& C,
    float& n0, float& n1, float& d0, float& d1)
{
    #pragma unroll 4
    for (int i = 0; i < nd; ++i) {
        uint2 Q = qp[i];                                   // uniform -> s_load
        unsigned vp = vrow[(size_t)i * (B_TOT / 2) + tid]; // coalesced dword
        sigpair(Q.x, Q.y, vp, C, n0, n1, d0, d1);
    }
}

// ---------------- prep: param transform + transposes ----------------
__global__ __launch_bounds__(256) void prep_all(
    const float* __restrict__ inputs, const float* __restrict__ hx,
    const float* __restrict__ input_w, const float* __restrict__ input_b,
    const float* __restrict__ s_mu, const float* __restrict__ s_sigma,
    const float* __restrict__ s_W, const float* __restrict__ s_erev,
    const float* __restrict__ mu, const float* __restrict__ sigma,
    const float* __restrict__ W, const float* __restrict__ erev,
    char* __restrict__ ws)
{
    __shared__ float tA[32][33], tB[32][33], tC[32][33];
    const int bid = blockIdx.x;
    const int tx = threadIdx.x & 31, ty = threadIdx.x >> 5;   // 32 x 8

    if (bid < 320) {
        bool rec = bid < 256;
        int b2  = rec ? bid : bid - 256;
        int tri = b2 >> 4;            // i-tile
        int tcj = b2 & 15;            // j-tile
        const float* sgp = rec ? sigma : s_sigma;
        const float* mup = rec ? mu    : s_mu;
        const float* wp  = rec ? W     : s_W;
        const float* erp = rec ? erev  : s_erev;
        #pragma unroll
        for (int rr = 0; rr < 4; ++rr) {
            int r = ty + rr * 8;
            int idx = (tri * 32 + r) * S_DIM + tcj * 32 + tx;
            float sg = sgp[idx], m = mup[idx], w = wp[idx], er = erp[idx];
            tA[r][tx] = -sg * L2E;
            tB[r][tx] = sg * m * L2E;
            tC[r][tx] = w * er;
        }
        __syncthreads();
        uint2* dst = (uint2*)(ws + (rec ? BY_RECH : BY_SENH));
        int ld = rec ? S_DIM : I_DIM;
        #pragma unroll
        for (int rr = 0; rr < 4; ++rr) {
            int jj = ty + rr * 8;
            float A = tA[tx][jj], Cc = tB[tx][jj], wn = tC[tx][jj];
            __half2 ac = __floats2half2_rn(A, Cc);
            __half2 ww = __floats2half2_rn(-wn, -fabsf(wn));
            dst[(size_t)(tcj * 32 + jj) * ld + tri * 32 + tx] =
                make_uint2(__builtin_bit_cast(unsigned, ac),
                           __builtin_bit_cast(unsigned, ww));
        }
    } else if (bid < 448) {
        // xh[i][b] = f16(inputs[b][i]*w[i]+b[i])
        int b2 = bid - 320;
        int tbr = b2 >> 2, tci = b2 & 3;
        int i = tci * 32 + tx;
        float wi = input_w[i], bi = input_b[i];
        #pragma unroll
        for (int rr = 0; rr < 4; ++rr) {
            int r = ty + rr * 8;
            tA[r][tx] = inputs[(tbr * 32 + r) * I_DIM + i] * wi + bi;
        }
        __syncthreads();
        __half* xh = (__half*)(ws + BY_XH);
        #pragma unroll
        for (int rr = 0; rr < 4; ++rr) {
            int ii = ty + rr * 8;
            xh[(size_t)(tci * 32 + ii) * B_TOT + tbr * 32 + tx] =
                __float2half_rn(tA[tx][ii]);
        }
    } else {
        // vA[j][b] = f16(hx[b][j])
        int b2 = bid - 448;
        int tbr = b2 >> 4, tcj = b2 & 15;
        #pragma unroll
        for (int rr = 0; rr < 4; ++rr) {
            int r = ty + rr * 8;
            tA[r][tx] = hx[(tbr * 32 + r) * S_DIM + tcj * 32 + tx];
        }
        __syncthreads();
        __half* va = (__half*)(ws + BY_VA);
        #pragma unroll
        for (int rr = 0; rr < 4; ++rr) {
            int jj = ty + rr * 8;
            va[(size_t)(tcj * 32 + jj) * B_TOT + tbr * 32 + tx] =
                __float2half_rn(tA[tx][jj]);
        }
    }
}

// ---------------- sensory (once) ----------------
__global__ __launch_bounds__(512, 4) void sensory_f16(char* __restrict__ ws)
{
    const int j = blockIdx.x, tid = threadIdx.x, tb = tid * 2;
    Cst C = mkc();
    const uint2* qp = (const uint2*)(ws + BY_SENH) + (size_t)j * I_DIM;
    const unsigned* xrow = (const unsigned*)(ws + BY_XH);
    float n0 = 0.f, n1 = 0.f, d0 = 0.f, d1 = 0.f;
    reduce_f16(qp, xrow, I_DIM, tid, C, n0, n1, d0, d1);
    float* SN = (float*)(ws + BY_SN);
    float* SD = (float*)(ws + BY_SD);
    *(float2*)&SN[(size_t)j * B_TOT + tb] = make_float2(n0, n1);
    *(float2*)&SD[(size_t)j * B_TOT + tb] = make_float2(d0, d1);
}

// ---------------- one unfold ----------------
__global__ __launch_bounds__(512, 4) void unfold_f16(
    const char* __restrict__ ws, const unsigned* __restrict__ vsrc,
    unsigned* __restrict__ vdst,
    const float* __restrict__ gleak, const float* __restrict__ vleak,
    const float* __restrict__ cm_t,
    float* __restrict__ out, int write_out)
{
    const int j = blockIdx.x, tid = threadIdx.x, tb = tid * 2;
    Cst C = mkc();
    const uint2* qp = (const uint2*)(ws + BY_RECH) + (size_t)j * S_DIM;
    const float* SN = (const float*)(ws + BY_SN);
    const float* SD = (const float*)(ws + BY_SD);
    float2 sn2 = *(const float2*)&SN[(size_t)j * B_TOT + tb];
    float2 sd2 = *(const float2*)&SD[(size_t)j * B_TOT + tb];
    float n0 = sn2.x, n1 = sn2.y, d0 = sd2.x, d1 = sd2.y;
    reduce_f16(qp, vsrc, S_DIM, tid, C, n0, n1, d0, d1);

    unsigned vop = vsrc[(size_t)j * (B_TOT / 2) + tid];
    __half2 voh = __builtin_bit_cast(__half2, vop);
    float vo0 = __half2float(voh.x), vo1 = __half2float(voh.y);
    float gl = gleak[j], vl = vleak[j], cm = cm_t[j];
    float glvl = gl * vl, cg = cm + gl;

    float r0 = (fmaf(cm, vo0, glvl) + n0) / (cg + d0);
    float r1 = (fmaf(cm, vo1, glvl) + n1) / (cg + d1);

    if (write_out) {
        out[tb * S_DIM + j] = r0;
        out[(tb + 1) * S_DIM + j] = r1;
    } else {
        vdst[(size_t)j * (B_TOT / 2) + tid] =
            __builtin_bit_cast(unsigned, __floats2half2_rn(r0, r1));
    }
}

extern "C" void kernel_launch(void* const* d_in, const int* in_sizes, int n_in,
                              void* d_out, int out_size, void* d_ws, size_t ws_size,
                              hipStream_t stream) {
    const float* inputs   = (const float*)d_in[0];
    const float* hx       = (const float*)d_in[1];
    const float* input_w  = (const float*)d_in[2];
    const float* input_b  = (const float*)d_in[3];
    const float* s_mu     = (const float*)d_in[4];
    const float* s_sigma  = (const float*)d_in[5];
    const float* s_W      = (const float*)d_in[6];
    const float* s_erev   = (const float*)d_in[7];
    const float* mu       = (const float*)d_in[8];
    const float* sigma    = (const float*)d_in[9];
    const float* W        = (const float*)d_in[10];
    const float* erev     = (const float*)d_in[11];
    const float* vleak    = (const float*)d_in[12];
    const float* gleak    = (const float*)d_in[13];
    const float* cm_t     = (const float*)d_in[14];
    float* out = (float*)d_out;
    char* ws   = (char*)d_ws;

    prep_all<<<960, 256, 0, stream>>>(inputs, hx, input_w, input_b,
                                      s_mu, s_sigma, s_W, s_erev,
                                      mu, sigma, W, erev, ws);

    sensory_f16<<<S_DIM, 512, 0, stream>>>(ws);

    unsigned* vA = (unsigned*)(ws + BY_VA);
    unsigned* vB = (unsigned*)(ws + BY_VB);
    for (int u = 0; u < UNFOLDS; ++u) {
        const unsigned* src = (u & 1) ? vB : vA;
        unsigned* dst       = (u & 1) ? vA : vB;
        int last = (u == UNFOLDS - 1);
        unfold_f16<<<S_DIM, 512, 0, stream>>>(
            ws, src, dst, gleak, vleak, cm_t, out, last);
    }
}

// Round 11
// 435.818 us; speedup vs baseline: 1.3108x; 1.3108x over previous
//
#include <hip/hip_runtime.h>
#include <math.h>

// LiquidNet2: B=1024, I=128, S=512, UNFOLDS=6, out v[B,S] fp32.
//
// Block = postsynaptic neuron j (512 blocks), thread = batch PAIR (512 thr).
// Sigmoid via NEAREST-lookup LDS table, 512 entries x 32 replicas f32 (64 KB):
//   f = A'*v + C'   (A' = -sigma*log2e*SCALE, C' = sigma*mu*log2e*SCALE+256.5)
//   f = med3(f, 0, 511); k = (u32)f   (round-to-nearest baked into C')
//   s = tbl[k*32 + (lane&31)]  -> dword bank = lane&31 for ANY k: ZERO
//   conflicts by construction (proven round 5), at 64 KB -> 2 blocks/CU.
// Per element: fma, med3, cvt, lshl_add, ds_read_b32, 2 fmac = 7 VALU + 1 DS.
// Params float4 (A',C',Wn,Wp) in [j][i] order -> wave-uniform s_load_dwordx4.
// v fp32 transposed vT[S][B]; 6 stream-ordered unfold launches ping-ponging.

#define B_TOT 1024
#define I_DIM 128
#define S_DIM 512
#define UNFOLDS 6
#define L2E 1.4426950408889634f
#define TBL_N 512
#define NREP 32
#define T_MAX 14.0f

// ---- ws float offsets; vB overlays sensQ+xT (dead after sensory) ----
#define OFF_RECQ 0                                   // 512*512*4 = 4 MiB
#define OFF_VA   (OFF_RECQ + S_DIM * S_DIM * 4)      // 2 MiB
#define OFF_SN   (OFF_VA + S_DIM * B_TOT)            // 2 MiB
#define OFF_SD   (OFF_SN + S_DIM * B_TOT)            // 2 MiB
#define OFF_SENQ (OFF_SD + S_DIM * B_TOT)            // 512*128*4 = 1 MiB
#define OFF_XT   (OFF_SENQ + S_DIM * I_DIM * 4)      // 0.5 MiB
#define OFF_VB   OFF_SENQ                            // 2 MiB overlay
// max extent = 12.0 MiB (same footprint proven in rounds 7-10)

// ---------------- prep: param transform + transposes ----------------
__global__ __launch_bounds__(256) void prep_all(
    const float* __restrict__ inputs, const float* __restrict__ hx,
    const float* __restrict__ input_w, const float* __restrict__ input_b,
    const float* __restrict__ s_mu, const float* __restrict__ s_sigma,
    const float* __restrict__ s_W, const float* __restrict__ s_erev,
    const float* __restrict__ mu, const float* __restrict__ sigma,
    const float* __restrict__ W, const float* __restrict__ erev,
    float* __restrict__ ws)
{
    __shared__ float tA[32][33], tB[32][33], tC[32][33];
    const int bid = blockIdx.x;
    const int tx = threadIdx.x & 31, ty = threadIdx.x >> 5;   // 32 x 8
    const float SCALE = (float)TBL_N / (2.0f * T_MAX);        // 18.2857
    const float COFF  = (float)(TBL_N / 2) + 0.5f;            // 256.5

    if (bid < 320) {
        // params: src [i][j] row-major -> dst [j][i] float4 (A',C',Wn,Wp)
        bool rec = bid < 256;
        int b2  = rec ? bid : bid - 256;
        int tri = b2 >> 4;            // i-tile
        int tcj = b2 & 15;            // j-tile
        const float* sgp = rec ? sigma : s_sigma;
        const float* mup = rec ? mu    : s_mu;
        const float* wp  = rec ? W     : s_W;
        const float* erp = rec ? erev  : s_erev;
        #pragma unroll
        for (int rr = 0; rr < 4; ++rr) {
            int r = ty + rr * 8;
            int idx = (tri * 32 + r) * S_DIM + tcj * 32 + tx;
            float sg = sgp[idx], m = mup[idx], w = wp[idx], er = erp[idx];
            tA[r][tx] = -sg * L2E * SCALE;
            tB[r][tx] = sg * m * L2E * SCALE + COFF;
            tC[r][tx] = w * er;
        }
        __syncthreads();
        float4* dst = (float4*)(ws + (rec ? OFF_RECQ : OFF_SENQ));
        int ld = rec ? S_DIM : I_DIM;
        #pragma unroll
        for (int rr = 0; rr < 4; ++rr) {
            int jj = ty + rr * 8;
            float wn = tC[tx][jj];
            dst[(size_t)(tcj * 32 + jj) * ld + tri * 32 + tx] =
                make_float4(tA[tx][jj], tB[tx][jj], wn, fabsf(wn));
        }
    } else if (bid < 448) {
        // xT[i][b] = inputs[b][i]*w[i]+b[i]
        int b2 = bid - 320;
        int tbr = b2 >> 2, tci = b2 & 3;
        int i = tci * 32 + tx;
        float wi = input_w[i], bi = input_b[i];
        #pragma unroll
        for (int rr = 0; rr < 4; ++rr) {
            int r = ty + rr * 8;
            tA[r][tx] = inputs[(tbr * 32 + r) * I_DIM + i] * wi + bi;
        }
        __syncthreads();
        float* xT = ws + OFF_XT;
        #pragma unroll
        for (int rr = 0; rr < 4; ++rr) {
            int ii = ty + rr * 8;
            xT[(size_t)(tci * 32 + ii) * B_TOT + tbr * 32 + tx] = tA[tx][ii];
        }
    } else {
        // vA[j][b] = hx[b][j]
        int b2 = bid - 448;
        int tbr = b2 >> 4, tcj = b2 & 15;
        #pragma unroll
        for (int rr = 0; rr < 4; ++rr) {
            int r = ty + rr * 8;
            tA[r][tx] = hx[(tbr * 32 + r) * S_DIM + tcj * 32 + tx];
        }
        __syncthreads();
        float* vA = ws + OFF_VA;
        #pragma unroll
        for (int rr = 0; rr < 4; ++rr) {
            int jj = ty + rr * 8;
            vA[(size_t)(tcj * 32 + jj) * B_TOT + tbr * 32 + tx] = tA[tx][jj];
        }
    }
}

// ---------------- table build: 512 entries x 32 reps, f32 ----------------
__device__ __forceinline__ void build_tbl(float* tbl, int tid)
{
    // entry k = s(t_k), t_k = (k - 256) / SCALE ; one entry per thread
    const float INV_SCALE = (2.0f * T_MAX) / (float)TBL_N;
    int k = tid;                     // 512 threads, 512 entries
    float s = 1.0f / (1.0f + exp2f((float)(k - TBL_N / 2) * INV_SCALE));
    #pragma unroll
    for (int r = 0; r < NREP; ++r)
        tbl[k * NREP + ((tid + r) & (NREP - 1))] = s;
}

// one element: nearest-table sigmoid + accumulate
__device__ __forceinline__ void sig_elem(float A, float C, float Wn, float Wp,
                                         float v, const char* tbase, float CLHI,
                                         float& n, float& d)
{
    float f = fmaf(A, v, C);
    f = __builtin_amdgcn_fmed3f(f, 0.0f, CLHI);
    unsigned k = (unsigned)f;                         // trunc; rounding in C'
    float s = *(const float*)(tbase + (k << 7));      // k*NREP*4 ; bank=lane&31
    n = fmaf(Wn, s, n);
    d = fmaf(Wp, s, d);
}

__device__ __forceinline__ void col_reduce_tbl(
    const float4* __restrict__ qp,   // [nd] records for this j (uniform)
    const float* __restrict__ vsrc,  // [nd][B_TOT]
    int nd, int tb, const char* tbase, float CLHI,
    float& n0, float& n1, float& d0, float& d1)
{
    #pragma unroll 4
    for (int i = 0; i < nd; ++i) {
        float4 q = qp[i];                             // wave-uniform -> s_load
        float2 v = *(const float2*)(vsrc + (size_t)i * B_TOT + tb);
        sig_elem(q.x, q.y, q.z, q.w, v.x, tbase, CLHI, n0, d0);
        sig_elem(q.x, q.y, q.z, q.w, v.y, tbase, CLHI, n1, d1);
    }
}

// ---------------- sensory (once) ----------------
__global__ __launch_bounds__(512) void sensory_kernel(float* __restrict__ ws)
{
    __shared__ float tbl[TBL_N * NREP];               // 64 KB
    const int tid = threadIdx.x, j = blockIdx.x, tb = tid * 2;
    build_tbl(tbl, tid);
    __syncthreads();
    const char* tbase = (const char*)tbl + ((tid & (NREP - 1)) << 2);
    const float CLHI = (float)(TBL_N - 1);
    float n0 = 0.f, n1 = 0.f, d0 = 0.f, d1 = 0.f;
    col_reduce_tbl((const float4*)(ws + OFF_SENQ) + (size_t)j * I_DIM,
                   ws + OFF_XT, I_DIM, tb, tbase, CLHI, n0, n1, d0, d1);
    *(float2*)&ws[OFF_SN + (size_t)j * B_TOT + tb] = make_float2(n0, n1);
    *(float2*)&ws[OFF_SD + (size_t)j * B_TOT + tb] = make_float2(d0, d1);
}

// ---------------- one unfold ----------------
__global__ __launch_bounds__(512) void unfold_kernel(
    const float* __restrict__ ws, const float* __restrict__ vsrc,
    float* __restrict__ vdst,
    const float* __restrict__ gleak, const float* __restrict__ vleak,
    const float* __restrict__ cm_t,
    float* __restrict__ out, int write_out)
{
    __shared__ float tbl[TBL_N * NREP];               // 64 KB
    const int tid = threadIdx.x, j = blockIdx.x, tb = tid * 2;
    build_tbl(tbl, tid);
    __syncthreads();
    const char* tbase = (const char*)tbl + ((tid & (NREP - 1)) << 2);
    const float CLHI = (float)(TBL_N - 1);

    float2 sn = *(const float2*)&ws[OFF_SN + (size_t)j * B_TOT + tb];
    float2 sd = *(const float2*)&ws[OFF_SD + (size_t)j * B_TOT + tb];
    float n0 = sn.x, n1 = sn.y, d0 = sd.x, d1 = sd.y;
    col_reduce_tbl((const float4*)(ws + OFF_RECQ) + (size_t)j * S_DIM,
                   vsrc, S_DIM, tb, tbase, CLHI, n0, n1, d0, d1);

    float2 vo = *(const float2*)&vsrc[(size_t)j * B_TOT + tb];
    float gl = gleak[j], vl = vleak[j], cm = cm_t[j];
    float glvl = gl * vl, cg = cm + gl;

    float r0 = (fmaf(cm, vo.x, glvl) + n0) / (cg + d0);
    float r1 = (fmaf(cm, vo.y, glvl) + n1) / (cg + d1);

    if (write_out) {
        out[tb * S_DIM + j] = r0;
        out[(tb + 1) * S_DIM + j] = r1;
    } else {
        *(float2*)&vdst[(size_t)j * B_TOT + tb] = make_float2(r0, r1);
    }
}

extern "C" void kernel_launch(void* const* d_in, const int* in_sizes, int n_in,
                              void* d_out, int out_size, void* d_ws, size_t ws_size,
                              hipStream_t stream) {
    const float* inputs   = (const float*)d_in[0];
    const float* hx       = (const float*)d_in[1];
    const float* input_w  = (const float*)d_in[2];
    const float* input_b  = (const float*)d_in[3];
    const float* s_mu     = (const float*)d_in[4];
    const float* s_sigma  = (const float*)d_in[5];
    const float* s_W      = (const float*)d_in[6];
    const float* s_erev   = (const float*)d_in[7];
    const float* mu       = (const float*)d_in[8];
    const float* sigma    = (const float*)d_in[9];
    const float* W        = (const float*)d_in[10];
    const float* erev     = (const float*)d_in[11];
    const float* vleak    = (const float*)d_in[12];
    const float* gleak    = (const float*)d_in[13];
    const float* cm_t     = (const float*)d_in[14];
    float* out = (float*)d_out;
    float* ws  = (float*)d_ws;

    prep_all<<<960, 256, 0, stream>>>(inputs, hx, input_w, input_b,
                                      s_mu, s_sigma, s_W, s_erev,
                                      mu, sigma, W, erev, ws);

    sensory_kernel<<<S_DIM, 512, 0, stream>>>(ws);

    float* vA = ws + OFF_VA;
    float* vB = ws + OFF_VB;
    for (int u = 0; u < UNFOLDS; ++u) {
        const float* src = (u & 1) ? vB : vA;
        float* dst       = (u & 1) ? vA : vB;
        int last = (u == UNFOLDS - 1);
        unfold_kernel<<<S_DIM, 512, 0, stream>>>(
            ws, src, dst, gleak, vleak, cm_t, out, last);
    }
}

// Round 12
// 407.424 us; speedup vs baseline: 1.4022x; 1.0697x over previous
//
#include <hip/hip_runtime.h>
#include <math.h>

// LiquidNet2: B=1024, I=128, S=512, UNFOLDS=6, out v[B,S] fp32.
//
// Block = postsynaptic neuron j (512 blocks), thread = batch PAIR (512 thr).
// Sigmoid via NEAREST-lookup LDS table, 512 entries x 32 replicas f32 (64 KB):
//   f = A'*v + C'; f = med3(f,0,511); k=(u32)f; s = tbl[k*32 + (lane&31)]
//   -> dword bank = lane&31 for ANY k: ZERO conflicts by construction.
// Inner loop SOFTWARE-PIPELINED in chunks of 8 i:
//   phase1: 8 param records (s_load) + 8 v float2 (VMEM)
//   phase2: 16 addresses + 16 ds_read_b32 issued back-to-back
//   phase3: 32 fmacs consume
// -> 16 outstanding gathers/wave amortize the ~120cyc DS latency that round 11
// exposed per-iteration (VALU 44.6us + DS 39.6us summed to 78us: no overlap).
// Params float4 (A',C',Wn,Wp) in [j][i] order; v fp32 transposed vT[S][B];
// 6 stream-ordered unfold launches ping-ponging vT.

#define B_TOT 1024
#define I_DIM 128
#define S_DIM 512
#define UNFOLDS 6
#define L2E 1.4426950408889634f
#define TBL_N 512
#define NREP 32
#define T_MAX 14.0f
#define CHUNK 8

// ---- ws float offsets; vB overlays sensQ+xT (dead after sensory) ----
#define OFF_RECQ 0                                   // 512*512*4 = 4 MiB
#define OFF_VA   (OFF_RECQ + S_DIM * S_DIM * 4)      // 2 MiB
#define OFF_SN   (OFF_VA + S_DIM * B_TOT)            // 2 MiB
#define OFF_SD   (OFF_SN + S_DIM * B_TOT)            // 2 MiB
#define OFF_SENQ (OFF_SD + S_DIM * B_TOT)            // 512*128*4 = 1 MiB
#define OFF_XT   (OFF_SENQ + S_DIM * I_DIM * 4)      // 0.5 MiB
#define OFF_VB   OFF_SENQ                            // 2 MiB overlay
// max extent = 12.0 MiB (footprint proven rounds 7-11)

// ---------------- prep: param transform + transposes ----------------
__global__ __launch_bounds__(256) void prep_all(
    const float* __restrict__ inputs, const float* __restrict__ hx,
    const float* __restrict__ input_w, const float* __restrict__ input_b,
    const float* __restrict__ s_mu, const float* __restrict__ s_sigma,
    const float* __restrict__ s_W, const float* __restrict__ s_erev,
    const float* __restrict__ mu, const float* __restrict__ sigma,
    const float* __restrict__ W, const float* __restrict__ erev,
    float* __restrict__ ws)
{
    __shared__ float tA[32][33], tB[32][33], tC[32][33];
    const int bid = blockIdx.x;
    const int tx = threadIdx.x & 31, ty = threadIdx.x >> 5;   // 32 x 8
    const float SCALE = (float)TBL_N / (2.0f * T_MAX);        // 18.2857
    const float COFF  = (float)(TBL_N / 2) + 0.5f;            // 256.5

    if (bid < 320) {
        // params: src [i][j] row-major -> dst [j][i] float4 (A',C',Wn,Wp)
        bool rec = bid < 256;
        int b2  = rec ? bid : bid - 256;
        int tri = b2 >> 4;            // i-tile
        int tcj = b2 & 15;            // j-tile
        const float* sgp = rec ? sigma : s_sigma;
        const float* mup = rec ? mu    : s_mu;
        const float* wp  = rec ? W     : s_W;
        const float* erp = rec ? erev  : s_erev;
        #pragma unroll
        for (int rr = 0; rr < 4; ++rr) {
            int r = ty + rr * 8;
            int idx = (tri * 32 + r) * S_DIM + tcj * 32 + tx;
            float sg = sgp[idx], m = mup[idx], w = wp[idx], er = erp[idx];
            tA[r][tx] = -sg * L2E * SCALE;
            tB[r][tx] = sg * m * L2E * SCALE + COFF;
            tC[r][tx] = w * er;
        }
        __syncthreads();
        float4* dst = (float4*)(ws + (rec ? OFF_RECQ : OFF_SENQ));
        int ld = rec ? S_DIM : I_DIM;
        #pragma unroll
        for (int rr = 0; rr < 4; ++rr) {
            int jj = ty + rr * 8;
            float wn = tC[tx][jj];
            dst[(size_t)(tcj * 32 + jj) * ld + tri * 32 + tx] =
                make_float4(tA[tx][jj], tB[tx][jj], wn, fabsf(wn));
        }
    } else if (bid < 448) {
        // xT[i][b] = inputs[b][i]*w[i]+b[i]
        int b2 = bid - 320;
        int tbr = b2 >> 2, tci = b2 & 3;
        int i = tci * 32 + tx;
        float wi = input_w[i], bi = input_b[i];
        #pragma unroll
        for (int rr = 0; rr < 4; ++rr) {
            int r = ty + rr * 8;
            tA[r][tx] = inputs[(tbr * 32 + r) * I_DIM + i] * wi + bi;
        }
        __syncthreads();
        float* xT = ws + OFF_XT;
        #pragma unroll
        for (int rr = 0; rr < 4; ++rr) {
            int ii = ty + rr * 8;
            xT[(size_t)(tci * 32 + ii) * B_TOT + tbr * 32 + tx] = tA[tx][ii];
        }
    } else {
        // vA[j][b] = hx[b][j]
        int b2 = bid - 448;
        int tbr = b2 >> 4, tcj = b2 & 15;
        #pragma unroll
        for (int rr = 0; rr < 4; ++rr) {
            int r = ty + rr * 8;
            tA[r][tx] = hx[(tbr * 32 + r) * S_DIM + tcj * 32 + tx];
        }
        __syncthreads();
        float* vA = ws + OFF_VA;
        #pragma unroll
        for (int rr = 0; rr < 4; ++rr) {
            int jj = ty + rr * 8;
            vA[(size_t)(tcj * 32 + jj) * B_TOT + tbr * 32 + tx] = tA[tx][jj];
        }
    }
}

// ---------------- table build: 512 entries x 32 reps, f32 ----------------
__device__ __forceinline__ void build_tbl(float* tbl, int tid)
{
    const float INV_SCALE = (2.0f * T_MAX) / (float)TBL_N;
    int k = tid;                     // 512 threads, 512 entries
    float s = 1.0f / (1.0f + exp2f((float)(k - TBL_N / 2) * INV_SCALE));
    #pragma unroll
    for (int r = 0; r < NREP; ++r)
        tbl[k * NREP + ((tid + r) & (NREP - 1))] = s;
}

// ---------------- pipelined column reduction ----------------
__device__ __forceinline__ void col_reduce_pipe(
    const float4* __restrict__ qp,   // [nd] records for this j (uniform)
    const float* __restrict__ vsrc,  // [nd][B_TOT]
    int nd, int tb, const char* tbase, float CLHI,
    float& n0, float& n1, float& d0, float& d1)
{
    for (int c = 0; c < nd; c += CHUNK) {
        float4 q[CHUNK];
        float2 vv[CHUNK];
        float ss0[CHUNK], ss1[CHUNK];
        // phase 1: params (s_load) + v rows (VMEM), all independent
        #pragma unroll
        for (int u = 0; u < CHUNK; ++u) {
            q[u]  = qp[c + u];
            vv[u] = *(const float2*)(vsrc + (size_t)(c + u) * B_TOT + tb);
        }
        // phase 2: 16 addresses -> 16 ds_read_b32 back-to-back
        #pragma unroll
        for (int u = 0; u < CHUNK; ++u) {
            float f0 = __builtin_amdgcn_fmed3f(fmaf(q[u].x, vv[u].x, q[u].y), 0.0f, CLHI);
            float f1 = __builtin_amdgcn_fmed3f(fmaf(q[u].x, vv[u].y, q[u].y), 0.0f, CLHI);
            ss0[u] = *(const float*)(tbase + (((unsigned)f0) << 7));
            ss1[u] = *(const float*)(tbase + (((unsigned)f1) << 7));
        }
        // phase 3: consume
        #pragma unroll
        for (int u = 0; u < CHUNK; ++u) {
            n0 = fmaf(q[u].z, ss0[u], n0);
            d0 = fmaf(q[u].w, ss0[u], d0);
            n1 = fmaf(q[u].z, ss1[u], n1);
            d1 = fmaf(q[u].w, ss1[u], d1);
        }
    }
}

// ---------------- sensory (once) ----------------
__global__ __launch_bounds__(512, 2) void sensory_kernel(float* __restrict__ ws)
{
    __shared__ float tbl[TBL_N * NREP];               // 64 KB
    const int tid = threadIdx.x, j = blockIdx.x, tb = tid * 2;
    build_tbl(tbl, tid);
    __syncthreads();
    const char* tbase = (const char*)tbl + ((tid & (NREP - 1)) << 2);
    const float CLHI = (float)(TBL_N - 1);
    float n0 = 0.f, n1 = 0.f, d0 = 0.f, d1 = 0.f;
    col_reduce_pipe((const float4*)(ws + OFF_SENQ) + (size_t)j * I_DIM,
                    ws + OFF_XT, I_DIM, tb, tbase, CLHI, n0, n1, d0, d1);
    *(float2*)&ws[OFF_SN + (size_t)j * B_TOT + tb] = make_float2(n0, n1);
    *(float2*)&ws[OFF_SD + (size_t)j * B_TOT + tb] = make_float2(d0, d1);
}

// ---------------- one unfold ----------------
__global__ __launch_bounds__(512, 2) void unfold_kernel(
    const float* __restrict__ ws, const float* __restrict__ vsrc,
    float* __restrict__ vdst,
    const float* __restrict__ gleak, const float* __restrict__ vleak,
    const float* __restrict__ cm_t,
    float* __restrict__ out, int write_out)
{
    __shared__ float tbl[TBL_N * NREP];               // 64 KB
    const int tid = threadIdx.x, j = blockIdx.x, tb = tid * 2;
    build_tbl(tbl, tid);
    __syncthreads();
    const char* tbase = (const char*)tbl + ((tid & (NREP - 1)) << 2);
    const float CLHI = (float)(TBL_N - 1);

    float2 sn = *(const float2*)&ws[OFF_SN + (size_t)j * B_TOT + tb];
    float2 sd = *(const float2*)&ws[OFF_SD + (size_t)j * B_TOT + tb];
    float n0 = sn.x, n1 = sn.y, d0 = sd.x, d1 = sd.y;
    col_reduce_pipe((const float4*)(ws + OFF_RECQ) + (size_t)j * S_DIM,
                    vsrc, S_DIM, tb, tbase, CLHI, n0, n1, d0, d1);

    float2 vo = *(const float2*)&vsrc[(size_t)j * B_TOT + tb];
    float gl = gleak[j], vl = vleak[j], cm = cm_t[j];
    float glvl = gl * vl, cg = cm + gl;

    float r0 = (fmaf(cm, vo.x, glvl) + n0) / (cg + d0);
    float r1 = (fmaf(cm, vo.y, glvl) + n1) / (cg + d1);

    if (write_out) {
        out[tb * S_DIM + j] = r0;
        out[(tb + 1) * S_DIM + j] = r1;
    } else {
        *(float2*)&vdst[(size_t)j * B_TOT + tb] = make_float2(r0, r1);
    }
}

extern "C" void kernel_launch(void* const* d_in, const int* in_sizes, int n_in,
                              void* d_out, int out_size, void* d_ws, size_t ws_size,
                              hipStream_t stream) {
    const float* inputs   = (const float*)d_in[0];
    const float* hx       = (const float*)d_in[1];
    const float* input_w  = (const float*)d_in[2];
    const float* input_b  = (const float*)d_in[3];
    const float* s_mu     = (const float*)d_in[4];
    const float* s_sigma  = (const float*)d_in[5];
    const float* s_W      = (const float*)d_in[6];
    const float* s_erev   = (const float*)d_in[7];
    const float* mu       = (const float*)d_in[8];
    const float* sigma    = (const float*)d_in[9];
    const float* W        = (const float*)d_in[10];
    const float* erev     = (const float*)d_in[11];
    const float* vleak    = (const float*)d_in[12];
    const float* gleak    = (const float*)d_in[13];
    const float* cm_t     = (const float*)d_in[14];
    float* out = (float*)d_out;
    float* ws  = (float*)d_ws;

    prep_all<<<960, 256, 0, stream>>>(inputs, hx, input_w, input_b,
                                      s_mu, s_sigma, s_W, s_erev,
                                      mu, sigma, W, erev, ws);

    sensory_kernel<<<S_DIM, 512, 0, stream>>>(ws);

    float* vA = ws + OFF_VA;
    float* vB = ws + OFF_VB;
    for (int u = 0; u < UNFOLDS; ++u) {
        const float* src = (u & 1) ? vB : vA;
        float* dst       = (u & 1) ? vA : vB;
        int last = (u == UNFOLDS - 1);
        unfold_kernel<<<S_DIM, 512, 0, stream>>>(
            ws, src, dst, gleak, vleak, cm_t, out, last);
    }
}